// Round 5
// baseline (531.657 us; speedup 1.0000x reference)
//
#include <hip/hip_runtime.h>
#include <math.h>

#define BB 16
#define NN 25200
#define NCLS 80
#define TOPK 1000
#define MAXDET 100
#define TIE_CAP 4096
#define CAND_CAP 1024
static constexpr float NEGV = -1000000000.0f;
static constexpr float IMGSZ = 640.0f;

struct Meta {
  unsigned b1;
  unsigned c_gt;
  unsigned cnt;
  unsigned tie_cnt;
};

__device__ __forceinline__ unsigned flipKey(float f) {
  unsigned u = __float_as_uint(f);
  return (u & 0x80000000u) ? ~u : (u | 0x80000000u);
}
__device__ __forceinline__ float unflipKey(unsigned k) {
  unsigned u = (k & 0x80000000u) ? (k & 0x7FFFFFFFu) : ~k;
  return __uint_as_float(u);
}

// 32-bit unsigned max DPP step (bound_ctrl=1 -> invalid lanes read 0 = identity)
#define UMAX_DPP(VAR, CTRL)                                                                   \
  {                                                                                           \
    unsigned _o = (unsigned)__builtin_amdgcn_update_dpp(0, (int)(VAR), CTRL, 0xF, 0xF, true); \
    if (_o > (VAR)) (VAR) = _o;                                                               \
  }

// (hi,lo) 64-bit-ordered max DPP step
#define U64MAX_DPP(H, L, CTRL)                                                                 \
  {                                                                                            \
    unsigned _oh = (unsigned)__builtin_amdgcn_update_dpp(0, (int)(H), CTRL, 0xF, 0xF, true);   \
    unsigned _ol = (unsigned)__builtin_amdgcn_update_dpp(0, (int)(L), CTRL, 0xF, 0xF, true);   \
    bool _g = (_oh > (H)) || ((_oh == (H)) && (_ol > (L)));                                    \
    (H) = _g ? _oh : (H);                                                                      \
    (L) = _g ? _ol : (L);                                                                      \
  }

// ---------------- phase 1: scores + high-16 histogram (4 lanes per row) ----------------
__global__ void __launch_bounds__(256) k_score(const float* __restrict__ regs,
                                               const float* __restrict__ clses,
                                               unsigned* __restrict__ keys,
                                               float* __restrict__ ccs,
                                               int* __restrict__ preds,
                                               unsigned* __restrict__ hist1) {
  int t = blockIdx.x * 256 + threadIdx.x;
  int row = t >> 2, q = t & 3;
  const float4* r4 = reinterpret_cast<const float4*>(clses + (size_t)row * NCLS);
  float best = -1.0f;
  int bi = 0;
#pragma unroll
  for (int u = 0; u < 5; ++u) {
    float4 v = r4[q + 4 * u];
    int b0 = (q + 4 * u) * 4;
    if (v.x > best) { best = v.x; bi = b0 + 0; }
    if (v.y > best) { best = v.y; bi = b0 + 1; }
    if (v.z > best) { best = v.z; bi = b0 + 2; }
    if (v.w > best) { best = v.w; bi = b0 + 3; }
  }
  // quad butterfly: value stage (positive-float bits are unsigned-orderable)
  unsigned vb = __float_as_uint(best);
  unsigned m = vb;
  UMAX_DPP(m, 0xB1);  // quad_perm [1,0,3,2]
  UMAX_DPP(m, 0x4E);  // quad_perm [2,3,0,1]
  unsigned t2 = (vb == m) ? (unsigned)(79 - bi) : 0u;
  UMAX_DPP(t2, 0xB1);
  UMAX_DPP(t2, 0x4E);
  if (q == 0) {
    float bestv = __uint_as_float(m);
    int bidx = 79 - (int)t2;
    float pobj = regs[(size_t)row * 5 + 4];
    float sc = pobj * bestv;
    float s = (sc >= 0.05f) ? sc : NEGV;
    unsigned key = flipKey(s);
    keys[row] = key;
    ccs[row] = bestv;
    preds[row] = bidx;
    int img = row / NN;
    atomicAdd(&hist1[(size_t)img * 65536 + (key >> 16)], 1u);
  }
}

// ---------------- histogram scan (single level): find cutoff high-16 bin ----------------
__global__ void __launch_bounds__(256) k_scan(const unsigned* __restrict__ hist,
                                              Meta* __restrict__ meta) {
  __shared__ unsigned part[256];
  __shared__ unsigned sfx[256];
  __shared__ int s_sel;
  __shared__ unsigned s_cum;
  int img = blockIdx.x;
  int t = threadIdx.x;
  const unsigned* h = hist + (size_t)img * 65536;
  const unsigned target = (unsigned)TOPK;
  unsigned s = 0;
  const uint4* h4 = reinterpret_cast<const uint4*>(h) + (size_t)t * 64;
  for (int j = 0; j < 64; ++j) {
    uint4 v = h4[j];
    s += v.x + v.y + v.z + v.w;
  }
  part[t] = s;
  sfx[t] = s;
  __syncthreads();
  for (int d = 1; d < 256; d <<= 1) {
    unsigned v = (t + d < 256) ? sfx[t + d] : 0u;
    __syncthreads();
    sfx[t] += v;
    __syncthreads();
  }
  {
    unsigned incl = sfx[t];
    unsigned excl = incl - part[t];
    if (incl >= target && excl < target) { s_sel = t; s_cum = excl; }
  }
  __syncthreads();
  int chunk = s_sel;
  unsigned cumAbove = s_cum;
  __syncthreads();
  unsigned b = h[(size_t)chunk * 256 + t];
  part[t] = b;
  sfx[t] = b;
  __syncthreads();
  for (int d = 1; d < 256; d <<= 1) {
    unsigned v = (t + d < 256) ? sfx[t + d] : 0u;
    __syncthreads();
    sfx[t] += v;
    __syncthreads();
  }
  {
    unsigned incl = cumAbove + sfx[t];
    unsigned excl = incl - part[t];
    if (incl >= target && excl < target) {
      meta[img].b1 = (unsigned)(chunk * 256 + t);
      meta[img].c_gt = excl;
    }
  }
}

// ---------------- decode + candidate write (global) ----------------
__device__ __forceinline__ void decode_write(int img, unsigned pos, int i,
                                             const float* __restrict__ regs,
                                             const float* __restrict__ anchors,
                                             float score, float cc, int pred,
                                             float* __restrict__ cand) {
  const size_t S = (size_t)BB * CAND_CAP;
  size_t g = (size_t)img * NN + (size_t)i;
  const float* r = regs + g * 5;
  float d0 = r[0], d1 = r[1], d2 = r[2], d3 = r[3], obj = r[4];
  const float* a = anchors + (size_t)i * 4;
  float ax1 = a[0], ay1 = a[1], ax2 = a[2], ay2 = a[3];
  float aw = ax2 - ax1, ah = ay2 - ay1;
  float acx = (ax1 + ax2) * 0.5f, acy = (ay1 + ay2) * 0.5f;
  float cx = acx + d0 * aw, cy = acy + d1 * ah;
  float w = aw * expf(d2), h = ah * expf(d3);
  float hw = 0.5f * w, hh = 0.5f * h;
  float x1 = fminf(fmaxf(cx - hw, 0.0f), IMGSZ);
  float y1 = fminf(fmaxf(cy - hh, 0.0f), IMGSZ);
  float x2 = fminf(fmaxf(cx + hw, 0.0f), IMGSZ);
  float y2 = fminf(fmaxf(cy + hh, 0.0f), IMGSZ);
  size_t o = (size_t)img * CAND_CAP + pos;
  cand[0 * S + o] = x1;
  cand[1 * S + o] = y1;
  cand[2 * S + o] = x2;
  cand[3 * S + o] = y2;
  cand[4 * S + o] = obj;
  cand[5 * S + o] = cc;
  cand[6 * S + o] = (float)pred;
  cand[7 * S + o] = score;
  reinterpret_cast<unsigned*>(cand + 8 * S)[o] = (unsigned)i;
}

// ---------------- compaction: definite candidates + bin ties ----------------
__global__ void k_compact(const float* __restrict__ regs, const float* __restrict__ anchors,
                          const unsigned* __restrict__ keys, const float* __restrict__ ccs,
                          const int* __restrict__ preds, Meta* __restrict__ meta,
                          float* __restrict__ cand, unsigned long long* __restrict__ ties) {
  int g = blockIdx.x * blockDim.x + threadIdx.x;
  if (g >= BB * NN) return;
  int img = g / NN;
  int i = g - img * NN;
  unsigned key = keys[g];
  unsigned k16 = key >> 16;
  unsigned b1 = meta[img].b1;
  if (k16 > b1) {
    unsigned pos = atomicAdd(&meta[img].cnt, 1u);
    if (pos < CAND_CAP)
      decode_write(img, pos, i, regs, anchors, unflipKey(key), ccs[g], preds[g], cand);
  } else if (k16 == b1) {
    unsigned tp = atomicAdd(&meta[img].tie_cnt, 1u);
    if (tp < TIE_CAP)
      ties[(size_t)img * TIE_CAP + tp] =
          ((unsigned long long)key << 15) | (unsigned long long)(0x7FFFu - (unsigned)i);
  }
}

// ---------------- NMS: ONE WAVE per image, zero barriers in the loop ----------------
// 16 candidates/lane in registers (slot s -> lane s&63, reg s>>6).
// Per iter: register local-max tree -> 6-step DPP wave reduce -> readlane ->
// broadcast LDS winner fetch -> 16 in-register division-free IoU tests.
// Prologue resolves bin-ties: wave-reduced 47-bit key (score desc, idx asc) selection,
// lane 0 decodes directly into LDS (no global round-trip, no fence needed).
__global__ void __launch_bounds__(64) k_nms(const float* __restrict__ cand,
                                            const Meta* __restrict__ meta,
                                            float* __restrict__ out,
                                            const float* __restrict__ regs,
                                            const float* __restrict__ anchors,
                                            const float* __restrict__ ccs,
                                            const int* __restrict__ preds,
                                            const unsigned long long* __restrict__ ties) {
  const size_t S = (size_t)BB * CAND_CAP;
  const int STR = 14;  // LDS floats per slot: x1o,y1o,x2o,y2o,area, x1,y1,x2,y2,obj,cc,cp, idx, score
  int img = blockIdx.x;
  int lane = threadIdx.x;

  __shared__ float lds[CAND_CAP * 14];       // 57344 B
  __shared__ float4 lout4[MAXDET * 7 / 4];   // 2800 B output staging
  float* lout = reinterpret_cast<float*>(lout4);

  unsigned cnt = meta[img].cnt;
  unsigned c_gt = meta[img].c_gt;
  unsigned tcnt = meta[img].tie_cnt;
  if (tcnt > TIE_CAP) tcnt = TIE_CAP;
  unsigned need = (unsigned)TOPK - c_gt;
  if (need > tcnt) need = tcnt;
  int n = (int)(cnt + need);

  float x1o[16], y1o[16], x2o[16], y2o[16], area[16];
  unsigned kh[16], kl[16];

  // ---- (1) main load: all 1024 slots (defaults where c >= cnt) ----
#pragma unroll
  for (int k = 0; k < 16; ++k) {
    int c = k * 64 + lane;
    size_t o = (size_t)img * CAND_CAP + (size_t)c;
    bool v = c < (int)cnt;
    float vx1 = cand[0 * S + o], vy1 = cand[1 * S + o];
    float vx2 = cand[2 * S + o], vy2 = cand[3 * S + o];
    float vobj = cand[4 * S + o], vcc = cand[5 * S + o];
    float vcp = cand[6 * S + o], vsc = cand[7 * S + o];
    unsigned vai = reinterpret_cast<const unsigned*>(cand + 8 * S)[o];
    if (!v) { vx1 = vy1 = vx2 = vy2 = 0.f; vobj = vcc = vcp = 0.f; vsc = NEGV; vai = 0x7FFFu; }
    float offv = vcp * 4096.0f;
    float a1 = vx1 + offv, b1 = vy1 + offv, a2 = vx2 + offv, b2 = vy2 + offv;
    float ar = (a2 - a1) * (b2 - b1);
    x1o[k] = a1; y1o[k] = b1; x2o[k] = a2; y2o[k] = b2; area[k] = ar;
    float* L = lds + (size_t)c * STR;
    L[0] = a1; L[1] = b1; L[2] = a2; L[3] = b2; L[4] = ar;
    L[5] = vx1; L[6] = vy1; L[7] = vx2; L[8] = vy2; L[9] = vobj; L[10] = vcc; L[11] = vcp;
    L[12] = __uint_as_float(vai);
    L[13] = vsc;
    kh[k] = flipKey(vsc);
    kl[k] = (((0x7FFFu - vai) & 0x7FFFu) << 10) | (unsigned)c;
  }

  // ---- (2) tie selection: full-key desc, anchor asc; lane 0 decodes into LDS ----
  {
    unsigned long long prev = ~0ull;
    const unsigned long long* tptr = ties + (size_t)img * TIE_CAP;
    for (unsigned j = 0; j < need; ++j) {
      unsigned lh = 0u, ll = 0u;
      for (unsigned p = lane; p < tcnt; p += 64) {
        unsigned long long pk = tptr[p];
        if (pk < prev) {
          unsigned ph = (unsigned)(pk >> 32), pl = (unsigned)pk;
          if (ph > lh || (ph == lh && pl > ll)) { lh = ph; ll = pl; }
        }
      }
      U64MAX_DPP(lh, ll, 0x111);
      U64MAX_DPP(lh, ll, 0x112);
      U64MAX_DPP(lh, ll, 0x114);
      U64MAX_DPP(lh, ll, 0x118);
      U64MAX_DPP(lh, ll, 0x142);
      U64MAX_DPP(lh, ll, 0x143);
      unsigned sh = (unsigned)__builtin_amdgcn_readlane((int)lh, 63);
      unsigned sl = (unsigned)__builtin_amdgcn_readlane((int)ll, 63);
      unsigned long long sel = (((unsigned long long)sh) << 32) | sl;
      prev = sel;
      unsigned idx = 0x7FFFu - (unsigned)(sel & 0x7FFFull);
      unsigned key32 = (unsigned)(sel >> 15);
      if (lane == 0) {
        size_t g = (size_t)img * NN + idx;
        const float* r = regs + g * 5;
        float d0 = r[0], d1 = r[1], d2 = r[2], d3 = r[3], obj = r[4];
        const float* a = anchors + (size_t)idx * 4;
        float ax1 = a[0], ay1 = a[1], ax2 = a[2], ay2 = a[3];
        float aw = ax2 - ax1, ah = ay2 - ay1;
        float acx = (ax1 + ax2) * 0.5f, acy = (ay1 + ay2) * 0.5f;
        float cx = acx + d0 * aw, cy = acy + d1 * ah;
        float w = aw * expf(d2), h = ah * expf(d3);
        float hw = 0.5f * w, hh = 0.5f * h;
        float x1 = fminf(fmaxf(cx - hw, 0.0f), IMGSZ);
        float y1 = fminf(fmaxf(cy - hh, 0.0f), IMGSZ);
        float x2 = fminf(fmaxf(cx + hw, 0.0f), IMGSZ);
        float y2 = fminf(fmaxf(cy + hh, 0.0f), IMGSZ);
        float cc = ccs[g];
        float cp = (float)preds[g];
        float offv = cp * 4096.0f;
        float a1 = x1 + offv, b1 = y1 + offv, a2 = x2 + offv, b2 = y2 + offv;
        float* L = lds + (size_t)(cnt + j) * STR;
        L[0] = a1; L[1] = b1; L[2] = a2; L[3] = b2;
        L[4] = (a2 - a1) * (b2 - b1);
        L[5] = x1; L[6] = y1; L[7] = x2; L[8] = y2; L[9] = obj; L[10] = cc; L[11] = cp;
        L[12] = __uint_as_float(idx);
        L[13] = unflipKey(key32);
      }
    }
  }
  __syncthreads();  // single-wave: cheap; publishes lane-0 LDS writes

  // ---- (3) tie reg-init: owning lanes pull their tie slots from LDS ----
#pragma unroll
  for (int k = 0; k < 16; ++k) {
    int c = k * 64 + lane;
    if (c >= (int)cnt && c < n) {
      const float* L = lds + (size_t)c * STR;
      x1o[k] = L[0]; y1o[k] = L[1]; x2o[k] = L[2]; y2o[k] = L[3]; area[k] = L[4];
      unsigned vai = __float_as_uint(L[12]);
      kh[k] = flipKey(L[13]);
      kl[k] = (((0x7FFFu - vai) & 0x7FFFu) << 10) | (unsigned)c;
    }
  }

  const unsigned validThr = flipKey(NEGV * 0.5f);

  // ---- (4) iteration loop: no barriers, no cross-wave traffic ----
  for (int it = 0; it < MAXDET; ++it) {
    // local max tree over 16 candidates (depth 4)
    unsigned ah[8], al[8];
#pragma unroll
    for (int k = 0; k < 8; ++k) {
      bool g = (kh[2 * k + 1] > kh[2 * k]) ||
               ((kh[2 * k + 1] == kh[2 * k]) && (kl[2 * k + 1] > kl[2 * k]));
      ah[k] = g ? kh[2 * k + 1] : kh[2 * k];
      al[k] = g ? kl[2 * k + 1] : kl[2 * k];
    }
#pragma unroll
    for (int k = 0; k < 4; ++k) {
      bool g = (ah[2 * k + 1] > ah[2 * k]) ||
               ((ah[2 * k + 1] == ah[2 * k]) && (al[2 * k + 1] > al[2 * k]));
      ah[k] = g ? ah[2 * k + 1] : ah[2 * k];
      al[k] = g ? al[2 * k + 1] : al[2 * k];
    }
    {
      bool g = (ah[1] > ah[0]) || ((ah[1] == ah[0]) && (al[1] > al[0]));
      ah[0] = g ? ah[1] : ah[0];
      al[0] = g ? al[1] : al[0];
      g = (ah[3] > ah[2]) || ((ah[3] == ah[2]) && (al[3] > al[2]));
      ah[2] = g ? ah[3] : ah[2];
      al[2] = g ? al[3] : al[2];
      g = (ah[2] > ah[0]) || ((ah[2] == ah[0]) && (al[2] > al[0]));
      ah[0] = g ? ah[2] : ah[0];
      al[0] = g ? al[2] : al[0];
    }
    unsigned mh = ah[0], ml = al[0];
    // wave64 max via DPP (result in lane 63)
    U64MAX_DPP(mh, ml, 0x111);
    U64MAX_DPP(mh, ml, 0x112);
    U64MAX_DPP(mh, ml, 0x114);
    U64MAX_DPP(mh, ml, 0x118);
    U64MAX_DPP(mh, ml, 0x142);
    U64MAX_DPP(mh, ml, 0x143);
    unsigned bh = (unsigned)__builtin_amdgcn_readlane((int)mh, 63);
    unsigned bl = (unsigned)__builtin_amdgcn_readlane((int)ml, 63);

    if (bh <= validThr) {  // rest of output rows are zeros
      for (int p = lane; p < (MAXDET - it) * 7; p += 64) lout[it * 7 + p] = 0.0f;
      break;
    }
    int slot = (int)(bl & 1023u);
    const float* L = lds + (size_t)slot * STR;
    float bx1o = L[0], by1o = L[1], bx2o = L[2], by2o = L[3], areaB = L[4];
    if (lane == 0) {
      float* row = lout + it * 7;
      row[0] = L[5]; row[1] = L[6]; row[2] = L[7]; row[3] = L[8];
      row[4] = L[9]; row[5] = L[10]; row[6] = L[11];
    }
#pragma unroll
    for (int k = 0; k < 16; ++k) {
      float lx = fmaxf(bx1o, x1o[k]), ly = fmaxf(by1o, y1o[k]);
      float rx = fminf(bx2o, x2o[k]), ry = fminf(by2o, y2o[k]);
      float iw = fmaxf(rx - lx, 0.f), ih = fmaxf(ry - ly, 0.f);
      float inter = iw * ih;
      float uu = areaB + area[k] - inter;
      float ss = fmaf(2.0f, inter, -uu);  // exact 2i-u in the decision region (Sterbenz)
      float tt = uu * 0x1p-24f;           // exact scale; RN(i/u)>0.5 <=> ss>tt
      bool sup = (uu > 0.f && ss > tt) || (slot == k * 64 + lane);
      if (sup) { kh[k] = 0u; kl[k] = 0u; }
    }
  }

  // ---- flush staged output rows to global ----
  __syncthreads();
  float4* go4 = reinterpret_cast<float4*>(out + (size_t)img * MAXDET * 7);
  for (int p = lane; p < MAXDET * 7 / 4; p += 64) go4[p] = lout4[p];
}

// ---------------- launch ----------------
extern "C" void kernel_launch(void* const* d_in, const int* in_sizes, int n_in,
                              void* d_out, int out_size, void* d_ws, size_t ws_size,
                              hipStream_t stream) {
  const float* regs = (const float*)d_in[0];
  const float* clses = (const float*)d_in[1];
  const float* anchors = (const float*)d_in[2];
  float* out = (float*)d_out;
  char* ws = (char*)d_ws;

  constexpr size_t HIST_BYTES = (size_t)BB * 65536 * 4;  // 4 MiB
  constexpr size_t META_OFF = HIST_BYTES;
  constexpr size_t META_BYTES = 1024;
  constexpr size_t KEYS_OFF = META_OFF + META_BYTES;
  constexpr size_t ARR_BYTES = (size_t)BB * NN * 4;
  constexpr size_t CCS_OFF = KEYS_OFF + ARR_BYTES;
  constexpr size_t PREDS_OFF = CCS_OFF + ARR_BYTES;
  constexpr size_t CAND_OFF = PREDS_OFF + ARR_BYTES;
  constexpr size_t CAND_BYTES = (size_t)10 * BB * CAND_CAP * 4;
  constexpr size_t TIES_OFF = CAND_OFF + CAND_BYTES;

  unsigned* hist1 = (unsigned*)(ws);
  Meta* meta = (Meta*)(ws + META_OFF);
  unsigned* keys = (unsigned*)(ws + KEYS_OFF);
  float* ccs = (float*)(ws + CCS_OFF);
  int* preds = (int*)(ws + PREDS_OFF);
  float* cand = (float*)(ws + CAND_OFF);
  unsigned long long* ties = (unsigned long long*)(ws + TIES_OFF);

  // zero hist1 + meta every launch (ws is not re-poisoned between replays)
  hipMemsetAsync(d_ws, 0, KEYS_OFF, stream);

  int blocks = (BB * NN + 255) / 256;
  k_score<<<BB * NN * 4 / 256, 256, 0, stream>>>(regs, clses, keys, ccs, preds, hist1);
  k_scan<<<BB, 256, 0, stream>>>(hist1, meta);
  k_compact<<<blocks, 256, 0, stream>>>(regs, anchors, keys, ccs, preds, meta, cand, ties);
  k_nms<<<BB, 64, 0, stream>>>(cand, meta, out, regs, anchors, ccs, preds, ties);
}

// Round 6
// 391.866 us; speedup vs baseline: 1.3567x; 1.3567x over previous
//
#include <hip/hip_runtime.h>
#include <math.h>

#define BB 16
#define NN 25200
#define NCLS 80
#define TOPK 1000
#define MAXDET 100
#define TIE_CAP 4096
#define CAND_CAP 1024
#define BPI_C 99    // blocks/img for k_compact: ceil(25200/256)
#define BPI_S 394   // blocks/img for k_score:  ceil(25200*4/256)
static constexpr float NEGV = -1000000000.0f;
static constexpr float IMGSZ = 640.0f;

struct Meta {
  unsigned b1;
  unsigned c_gt;
  unsigned cnt;
  unsigned tie_cnt;
};

__device__ __forceinline__ unsigned flipKey(float f) {
  unsigned u = __float_as_uint(f);
  return (u & 0x80000000u) ? ~u : (u | 0x80000000u);
}
__device__ __forceinline__ float unflipKey(unsigned k) {
  unsigned u = (k & 0x80000000u) ? (k & 0x7FFFFFFFu) : ~k;
  return __uint_as_float(u);
}

// 32-bit unsigned max DPP step (bound_ctrl=1 -> invalid lanes read 0 = identity)
#define UMAX_DPP(VAR, CTRL)                                                                   \
  {                                                                                           \
    unsigned _o = (unsigned)__builtin_amdgcn_update_dpp(0, (int)(VAR), CTRL, 0xF, 0xF, true); \
    if (_o > (VAR)) (VAR) = _o;                                                               \
  }

// (hi,lo) 64-bit-ordered max DPP step
#define U64MAX_DPP(H, L, CTRL)                                                                 \
  {                                                                                            \
    unsigned _oh = (unsigned)__builtin_amdgcn_update_dpp(0, (int)(H), CTRL, 0xF, 0xF, true);   \
    unsigned _ol = (unsigned)__builtin_amdgcn_update_dpp(0, (int)(L), CTRL, 0xF, 0xF, true);   \
    bool _g = (_oh > (H)) || ((_oh == (H)) && (_ol > (L)));                                    \
    (H) = _g ? _oh : (H);                                                                      \
    (L) = _g ? _ol : (L);                                                                      \
  }

// ---------------- phase 1: scores + high-16 histogram (4 lanes per row) ----------------
__global__ void __launch_bounds__(256) k_score(const float* __restrict__ regs,
                                               const float* __restrict__ clses,
                                               unsigned* __restrict__ keys,
                                               float* __restrict__ ccs,
                                               int* __restrict__ preds,
                                               unsigned* __restrict__ hist1) {
  int img = blockIdx.x / BPI_S;
  int t = (blockIdx.x % BPI_S) * 256 + threadIdx.x;
  int rl = t >> 2, q = t & 3;
  if (rl >= NN) return;
  size_t row = (size_t)img * NN + (size_t)rl;
  const float4* r4 = reinterpret_cast<const float4*>(clses + row * NCLS);
  float best = -1.0f;
  int bi = 0;
#pragma unroll
  for (int u = 0; u < 5; ++u) {
    float4 v = r4[q + 4 * u];
    int b0 = (q + 4 * u) * 4;
    if (v.x > best) { best = v.x; bi = b0 + 0; }
    if (v.y > best) { best = v.y; bi = b0 + 1; }
    if (v.z > best) { best = v.z; bi = b0 + 2; }
    if (v.w > best) { best = v.w; bi = b0 + 3; }
  }
  // quad butterfly: value stage (positive-float bits are unsigned-orderable)
  unsigned vb = __float_as_uint(best);
  unsigned m = vb;
  UMAX_DPP(m, 0xB1);  // quad_perm [1,0,3,2]
  UMAX_DPP(m, 0x4E);  // quad_perm [2,3,0,1]
  unsigned t2 = (vb == m) ? (unsigned)(79 - bi) : 0u;
  UMAX_DPP(t2, 0xB1);
  UMAX_DPP(t2, 0x4E);
  if (q == 0) {
    float bestv = __uint_as_float(m);
    int bidx = 79 - (int)t2;
    float pobj = regs[row * 5 + 4];
    float sc = pobj * bestv;
    float s = (sc >= 0.05f) ? sc : NEGV;
    unsigned key = flipKey(s);
    keys[row] = key;
    ccs[row] = bestv;
    preds[row] = bidx;
    atomicAdd(&hist1[(size_t)img * 65536 + (key >> 16)], 1u);
  }
}

// ---------------- histogram scan (single level): find cutoff high-16 bin ----------------
__global__ void __launch_bounds__(256) k_scan(const unsigned* __restrict__ hist,
                                              Meta* __restrict__ meta) {
  __shared__ unsigned part[256];
  __shared__ unsigned sfx[256];
  __shared__ int s_sel;
  __shared__ unsigned s_cum;
  int img = blockIdx.x;
  int t = threadIdx.x;
  const unsigned* h = hist + (size_t)img * 65536;
  const unsigned target = (unsigned)TOPK;
  unsigned s = 0;
  const uint4* h4 = reinterpret_cast<const uint4*>(h) + (size_t)t * 64;
  for (int j = 0; j < 64; ++j) {
    uint4 v = h4[j];
    s += v.x + v.y + v.z + v.w;
  }
  part[t] = s;
  sfx[t] = s;
  __syncthreads();
  for (int d = 1; d < 256; d <<= 1) {
    unsigned v = (t + d < 256) ? sfx[t + d] : 0u;
    __syncthreads();
    sfx[t] += v;
    __syncthreads();
  }
  {
    unsigned incl = sfx[t];
    unsigned excl = incl - part[t];
    if (incl >= target && excl < target) { s_sel = t; s_cum = excl; }
  }
  __syncthreads();
  int chunk = s_sel;
  unsigned cumAbove = s_cum;
  __syncthreads();
  unsigned b = h[(size_t)chunk * 256 + t];
  part[t] = b;
  sfx[t] = b;
  __syncthreads();
  for (int d = 1; d < 256; d <<= 1) {
    unsigned v = (t + d < 256) ? sfx[t + d] : 0u;
    __syncthreads();
    sfx[t] += v;
    __syncthreads();
  }
  {
    unsigned incl = cumAbove + sfx[t];
    unsigned excl = incl - part[t];
    if (incl >= target && excl < target) {
      meta[img].b1 = (unsigned)(chunk * 256 + t);
      meta[img].c_gt = excl;
    }
  }
}

// ---------------- decode + candidate write (global) ----------------
__device__ __forceinline__ void decode_write(int img, unsigned pos, int i,
                                             const float* __restrict__ regs,
                                             const float* __restrict__ anchors,
                                             float score, float cc, int pred,
                                             float* __restrict__ cand) {
  const size_t S = (size_t)BB * CAND_CAP;
  size_t g = (size_t)img * NN + (size_t)i;
  const float* r = regs + g * 5;
  float d0 = r[0], d1 = r[1], d2 = r[2], d3 = r[3], obj = r[4];
  const float* a = anchors + (size_t)i * 4;
  float ax1 = a[0], ay1 = a[1], ax2 = a[2], ay2 = a[3];
  float aw = ax2 - ax1, ah = ay2 - ay1;
  float acx = (ax1 + ax2) * 0.5f, acy = (ay1 + ay2) * 0.5f;
  float cx = acx + d0 * aw, cy = acy + d1 * ah;
  float w = aw * expf(d2), h = ah * expf(d3);
  float hw = 0.5f * w, hh = 0.5f * h;
  float x1 = fminf(fmaxf(cx - hw, 0.0f), IMGSZ);
  float y1 = fminf(fmaxf(cy - hh, 0.0f), IMGSZ);
  float x2 = fminf(fmaxf(cx + hw, 0.0f), IMGSZ);
  float y2 = fminf(fmaxf(cy + hh, 0.0f), IMGSZ);
  size_t o = (size_t)img * CAND_CAP + pos;
  cand[0 * S + o] = x1;
  cand[1 * S + o] = y1;
  cand[2 * S + o] = x2;
  cand[3 * S + o] = y2;
  cand[4 * S + o] = obj;
  cand[5 * S + o] = cc;
  cand[6 * S + o] = (float)pred;
  cand[7 * S + o] = score;
  reinterpret_cast<unsigned*>(cand + 8 * S)[o] = (unsigned)i;
}

// ---------------- compaction: wave-aggregated atomics (1 atomic/wave) ----------------
__global__ void k_compact(const float* __restrict__ regs, const float* __restrict__ anchors,
                          const unsigned* __restrict__ keys, const float* __restrict__ ccs,
                          const int* __restrict__ preds, Meta* __restrict__ meta,
                          float* __restrict__ cand, unsigned long long* __restrict__ ties) {
  int img = blockIdx.x / BPI_C;
  int i = (blockIdx.x % BPI_C) * 256 + threadIdx.x;
  if (i >= NN) return;
  int lane = threadIdx.x & 63;
  unsigned long long lt = (1ull << lane) - 1ull;
  size_t g = (size_t)img * NN + (size_t)i;
  unsigned key = keys[g];
  unsigned k16 = key >> 16;
  unsigned b1 = meta[img].b1;

  bool above = k16 > b1;
  unsigned long long mA = __ballot(above);
  if (above) {
    int leader = __builtin_ctzll(mA);
    unsigned base = 0;
    if (lane == leader) base = atomicAdd(&meta[img].cnt, (unsigned)__popcll(mA));
    base = __shfl(base, leader);
    unsigned pos = base + (unsigned)__popcll(mA & lt);
    if (pos < CAND_CAP)
      decode_write(img, pos, i, regs, anchors, unflipKey(key), ccs[g], preds[g], cand);
  }
  bool tie = (k16 == b1);
  unsigned long long mT = __ballot(tie);
  if (tie) {
    int leader = __builtin_ctzll(mT);
    unsigned base = 0;
    if (lane == leader) base = atomicAdd(&meta[img].tie_cnt, (unsigned)__popcll(mT));
    base = __shfl(base, leader);
    unsigned tp = base + (unsigned)__popcll(mT & lt);
    if (tp < TIE_CAP)
      ties[(size_t)img * TIE_CAP + tp] =
          ((unsigned long long)key << 15) | (unsigned long long)(0x7FFFu - (unsigned)i);
  }
}

// ---------------- NMS: ONE WAVE per image, boxes in LDS, keys in registers ----------------
// Per iter: phase-1 (15 v_max_u32 + 6 DPP-max) finds max score-key; phase-2 masked
// secondary ((0x7FFF-idx)<<10|slot) max resolves (idx asc) tie-break + winner slot.
// Winner box: broadcast LDS read. Suppression: 16 ds_read_b128 + in-register
// division-free exact IoU (RN(i/u)>0.5 <=> 2i-u > u*2^-24). Zero barriers in loop.
// Keys = 32 VGPR/lane; boxes NOT in registers (round-5 spill lesson).
__global__ void __launch_bounds__(64, 1) k_nms(const float* __restrict__ cand,
                                               const Meta* __restrict__ meta,
                                               float* __restrict__ out,
                                               const float* __restrict__ regs,
                                               const float* __restrict__ anchors,
                                               const float* __restrict__ ccs,
                                               const int* __restrict__ preds,
                                               const unsigned long long* __restrict__ ties) {
  const size_t S = (size_t)BB * CAND_CAP;
  int img = blockIdx.x;
  int lane = threadIdx.x;

  __shared__ float4 boxo[CAND_CAP];        // offset boxes (x1o,y1o,x2o,y2o)  16 KB
  __shared__ float4 pay0[CAND_CAP];        // x1,y1,x2,y2                     16 KB
  __shared__ float4 pay1[CAND_CAP];        // obj,cc,cp,score                 16 KB
  __shared__ unsigned idxA[CAND_CAP];      // anchor idx                       4 KB
  __shared__ float4 lout4[MAXDET * 7 / 4]; // output staging                 2.8 KB
  float* lout = reinterpret_cast<float*>(lout4);

  unsigned cnt = meta[img].cnt;
  unsigned c_gt = meta[img].c_gt;
  unsigned tcnt = meta[img].tie_cnt;
  if (tcnt > TIE_CAP) tcnt = TIE_CAP;
  unsigned need = (unsigned)TOPK - c_gt;
  if (need > tcnt) need = tcnt;
  int n = (int)(cnt + need);

  unsigned kh[16], kl[16];

  // ---- (1) main load: all 1024 slots (defaults where c >= cnt) ----
#pragma unroll
  for (int k = 0; k < 16; ++k) {
    int c = k * 64 + lane;
    size_t o = (size_t)img * CAND_CAP + (size_t)c;
    bool v = c < (int)cnt;
    float vx1 = cand[0 * S + o], vy1 = cand[1 * S + o];
    float vx2 = cand[2 * S + o], vy2 = cand[3 * S + o];
    float vobj = cand[4 * S + o], vcc = cand[5 * S + o];
    float vcp = cand[6 * S + o], vsc = cand[7 * S + o];
    unsigned vai = reinterpret_cast<const unsigned*>(cand + 8 * S)[o];
    if (!v) { vx1 = vy1 = vx2 = vy2 = 0.f; vobj = vcc = vcp = 0.f; vsc = NEGV; vai = 0x7FFFu; }
    float offv = vcp * 4096.0f;
    boxo[c] = make_float4(vx1 + offv, vy1 + offv, vx2 + offv, vy2 + offv);
    pay0[c] = make_float4(vx1, vy1, vx2, vy2);
    pay1[c] = make_float4(vobj, vcc, vcp, vsc);
    idxA[c] = vai;
    kh[k] = flipKey(vsc);
    kl[k] = (((0x7FFFu - vai) & 0x7FFFu) << 10) | (unsigned)c;
  }

  // ---- (2) tie selection: full-key desc, anchor asc; lane 0 decodes into LDS ----
  {
    unsigned long long prev = ~0ull;
    const unsigned long long* tptr = ties + (size_t)img * TIE_CAP;
    for (unsigned j = 0; j < need; ++j) {
      unsigned lh = 0u, ll = 0u;
      for (unsigned p = lane; p < tcnt; p += 64) {
        unsigned long long pk = tptr[p];
        if (pk < prev) {
          unsigned ph = (unsigned)(pk >> 32), pl = (unsigned)pk;
          if (ph > lh || (ph == lh && pl > ll)) { lh = ph; ll = pl; }
        }
      }
      U64MAX_DPP(lh, ll, 0x111);
      U64MAX_DPP(lh, ll, 0x112);
      U64MAX_DPP(lh, ll, 0x114);
      U64MAX_DPP(lh, ll, 0x118);
      U64MAX_DPP(lh, ll, 0x142);
      U64MAX_DPP(lh, ll, 0x143);
      unsigned sh = (unsigned)__builtin_amdgcn_readlane((int)lh, 63);
      unsigned sl = (unsigned)__builtin_amdgcn_readlane((int)ll, 63);
      unsigned long long sel = (((unsigned long long)sh) << 32) | sl;
      prev = sel;
      unsigned idx = 0x7FFFu - (unsigned)(sel & 0x7FFFull);
      unsigned key32 = (unsigned)(sel >> 15);
      if (lane == 0) {
        size_t g = (size_t)img * NN + idx;
        const float* r = regs + g * 5;
        float d0 = r[0], d1 = r[1], d2 = r[2], d3 = r[3], obj = r[4];
        const float* a = anchors + (size_t)idx * 4;
        float ax1 = a[0], ay1 = a[1], ax2 = a[2], ay2 = a[3];
        float aw = ax2 - ax1, ah = ay2 - ay1;
        float acx = (ax1 + ax2) * 0.5f, acy = (ay1 + ay2) * 0.5f;
        float cx = acx + d0 * aw, cy = acy + d1 * ah;
        float w = aw * expf(d2), h = ah * expf(d3);
        float hw = 0.5f * w, hh = 0.5f * h;
        float x1 = fminf(fmaxf(cx - hw, 0.0f), IMGSZ);
        float y1 = fminf(fmaxf(cy - hh, 0.0f), IMGSZ);
        float x2 = fminf(fmaxf(cx + hw, 0.0f), IMGSZ);
        float y2 = fminf(fmaxf(cy + hh, 0.0f), IMGSZ);
        float cc = ccs[g];
        float cp = (float)preds[g];
        float offv = cp * 4096.0f;
        int c = (int)(cnt + j);
        boxo[c] = make_float4(x1 + offv, y1 + offv, x2 + offv, y2 + offv);
        pay0[c] = make_float4(x1, y1, x2, y2);
        pay1[c] = make_float4(obj, cc, cp, unflipKey(key32));
        idxA[c] = idx;
      }
    }
  }
  __syncthreads();  // single wave: cheap; publishes lane-0 LDS writes

  // ---- (3) tie reg-init: owning lanes rebuild keys for tie slots ----
#pragma unroll
  for (int k = 0; k < 16; ++k) {
    int c = k * 64 + lane;
    if (c >= (int)cnt && c < n) {
      float4 p1 = pay1[c];
      unsigned vai = idxA[c];
      kh[k] = flipKey(p1.w);
      kl[k] = (((0x7FFFu - vai) & 0x7FFFu) << 10) | (unsigned)c;
    }
  }

  const unsigned validThr = flipKey(NEGV * 0.5f);

  // ---- (4) iteration loop: no barriers, no spills ----
  for (int it = 0; it < MAXDET; ++it) {
    // phase 1: max score-key over lane's 16, then wave DPP max (result lane 63)
    unsigned m1 = kh[0];
#pragma unroll
    for (int k = 1; k < 16; ++k) m1 = (kh[k] > m1) ? kh[k] : m1;
    UMAX_DPP(m1, 0x111);
    UMAX_DPP(m1, 0x112);
    UMAX_DPP(m1, 0x114);
    UMAX_DPP(m1, 0x118);
    UMAX_DPP(m1, 0x142);
    UMAX_DPP(m1, 0x143);
    unsigned bh = (unsigned)__builtin_amdgcn_readlane((int)m1, 63);
    if (bh <= validThr) {  // rest of output rows are zeros
      for (int p = lane; p < (MAXDET - it) * 7; p += 64) lout[it * 7 + p] = 0.0f;
      break;
    }
    // phase 2: among kh==bh, max secondary ((0x7FFF-idx)<<10 | slot)
    unsigned m2 = 0;
#pragma unroll
    for (int k = 0; k < 16; ++k) {
      unsigned s2 = (kh[k] == bh) ? kl[k] : 0u;
      m2 = (s2 > m2) ? s2 : m2;
    }
    UMAX_DPP(m2, 0x111);
    UMAX_DPP(m2, 0x112);
    UMAX_DPP(m2, 0x114);
    UMAX_DPP(m2, 0x118);
    UMAX_DPP(m2, 0x142);
    UMAX_DPP(m2, 0x143);
    unsigned bl = (unsigned)__builtin_amdgcn_readlane((int)m2, 63);
    int slot = (int)(bl & 1023u);

    float4 B = boxo[slot];  // broadcast LDS read (uniform addr)
    float areaB = (B.z - B.x) * (B.w - B.y);
    if (lane == 0) {
      float4 p0 = pay0[slot];
      float4 p1 = pay1[slot];
      float* row = lout + it * 7;
      row[0] = p0.x; row[1] = p0.y; row[2] = p0.z; row[3] = p0.w;
      row[4] = p1.x; row[5] = p1.y; row[6] = p1.z;
    }
#pragma unroll
    for (int k = 0; k < 16; ++k) {
      int c = k * 64 + lane;
      float4 q = boxo[c];
      float lx = fmaxf(B.x, q.x), ly = fmaxf(B.y, q.y);
      float rx = fminf(B.z, q.z), ry = fminf(B.w, q.w);
      float iw = fmaxf(rx - lx, 0.f), ih = fmaxf(ry - ly, 0.f);
      float inter = iw * ih;
      float areaK = (q.z - q.x) * (q.w - q.y);
      float uu = areaB + areaK - inter;
      float ss = fmaf(2.0f, inter, -uu);  // exact 2i-u in the decision region (Sterbenz)
      float tt = uu * 0x1p-24f;           // exact scale; RN(i/u)>0.5 <=> ss>tt
      bool sup = (uu > 0.f && ss > tt) || (c == slot);
      if (sup) kh[k] = 0u;
    }
  }

  // ---- flush staged output rows to global ----
  __syncthreads();
  float4* go4 = reinterpret_cast<float4*>(out + (size_t)img * MAXDET * 7);
  for (int p = lane; p < MAXDET * 7 / 4; p += 64) go4[p] = lout4[p];
}

// ---------------- launch ----------------
extern "C" void kernel_launch(void* const* d_in, const int* in_sizes, int n_in,
                              void* d_out, int out_size, void* d_ws, size_t ws_size,
                              hipStream_t stream) {
  const float* regs = (const float*)d_in[0];
  const float* clses = (const float*)d_in[1];
  const float* anchors = (const float*)d_in[2];
  float* out = (float*)d_out;
  char* ws = (char*)d_ws;

  constexpr size_t HIST_BYTES = (size_t)BB * 65536 * 4;  // 4 MiB
  constexpr size_t META_OFF = HIST_BYTES;
  constexpr size_t META_BYTES = 1024;
  constexpr size_t KEYS_OFF = META_OFF + META_BYTES;
  constexpr size_t ARR_BYTES = (size_t)BB * NN * 4;
  constexpr size_t CCS_OFF = KEYS_OFF + ARR_BYTES;
  constexpr size_t PREDS_OFF = CCS_OFF + ARR_BYTES;
  constexpr size_t CAND_OFF = PREDS_OFF + ARR_BYTES;
  constexpr size_t CAND_BYTES = (size_t)10 * BB * CAND_CAP * 4;
  constexpr size_t TIES_OFF = CAND_OFF + CAND_BYTES;

  unsigned* hist1 = (unsigned*)(ws);
  Meta* meta = (Meta*)(ws + META_OFF);
  unsigned* keys = (unsigned*)(ws + KEYS_OFF);
  float* ccs = (float*)(ws + CCS_OFF);
  int* preds = (int*)(ws + PREDS_OFF);
  float* cand = (float*)(ws + CAND_OFF);
  unsigned long long* ties = (unsigned long long*)(ws + TIES_OFF);

  // zero hist1 + meta every launch (ws is not re-poisoned between replays)
  hipMemsetAsync(d_ws, 0, KEYS_OFF, stream);

  k_score<<<BB * BPI_S, 256, 0, stream>>>(regs, clses, keys, ccs, preds, hist1);
  k_scan<<<BB, 256, 0, stream>>>(hist1, meta);
  k_compact<<<BB * BPI_C, 256, 0, stream>>>(regs, anchors, keys, ccs, preds, meta, cand, ties);
  k_nms<<<BB, 64, 0, stream>>>(cand, meta, out, regs, anchors, ccs, preds, ties);
}

// Round 7
// 221.569 us; speedup vs baseline: 2.3995x; 1.7686x over previous
//
#include <hip/hip_runtime.h>
#include <math.h>

#define BB 16
#define NN 25200
#define NCLS 80
#define TOPK 1000
#define MAXDET 100
#define TIE_CAP 4096
#define CAND_CAP 1024
#define BPI_C 99    // blocks/img for k_compact: ceil(25200/256)
#define BPI_S 394   // blocks/img for k_score:  ceil(25200*4/256)
static constexpr float NEGV = -1000000000.0f;
static constexpr float IMGSZ = 640.0f;

struct Meta {
  unsigned b1;
  unsigned c_gt;
  unsigned cnt;
  unsigned tie_cnt;
};

__device__ __forceinline__ unsigned flipKey(float f) {
  unsigned u = __float_as_uint(f);
  return (u & 0x80000000u) ? ~u : (u | 0x80000000u);
}
__device__ __forceinline__ float unflipKey(unsigned k) {
  unsigned u = (k & 0x80000000u) ? (k & 0x7FFFFFFFu) : ~k;
  return __uint_as_float(u);
}

// 32-bit unsigned max DPP step (bound_ctrl=1 -> invalid lanes read 0 = identity)
#define UMAX_DPP(VAR, CTRL)                                                                   \
  {                                                                                           \
    unsigned _o = (unsigned)__builtin_amdgcn_update_dpp(0, (int)(VAR), CTRL, 0xF, 0xF, true); \
    if (_o > (VAR)) (VAR) = _o;                                                               \
  }

// (hi,lo) 64-bit-ordered max DPP step
#define U64MAX_DPP(H, L, CTRL)                                                                 \
  {                                                                                            \
    unsigned _oh = (unsigned)__builtin_amdgcn_update_dpp(0, (int)(H), CTRL, 0xF, 0xF, true);   \
    unsigned _ol = (unsigned)__builtin_amdgcn_update_dpp(0, (int)(L), CTRL, 0xF, 0xF, true);   \
    bool _g = (_oh > (H)) || ((_oh == (H)) && (_ol > (L)));                                    \
    (H) = _g ? _oh : (H);                                                                      \
    (L) = _g ? _ol : (L);                                                                      \
  }

// ---------------- phase 1: scores + high-16 histogram (4 lanes per row) ----------------
__global__ void __launch_bounds__(256) k_score(const float* __restrict__ regs,
                                               const float* __restrict__ clses,
                                               unsigned* __restrict__ keys,
                                               float* __restrict__ ccs,
                                               int* __restrict__ preds,
                                               unsigned* __restrict__ hist1) {
  int img = blockIdx.x / BPI_S;
  int t = (blockIdx.x % BPI_S) * 256 + threadIdx.x;
  int rl = t >> 2, q = t & 3;
  if (rl >= NN) return;
  size_t row = (size_t)img * NN + (size_t)rl;
  const float4* r4 = reinterpret_cast<const float4*>(clses + row * NCLS);
  float best = -1.0f;
  int bi = 0;
#pragma unroll
  for (int u = 0; u < 5; ++u) {
    float4 v = r4[q + 4 * u];
    int b0 = (q + 4 * u) * 4;
    if (v.x > best) { best = v.x; bi = b0 + 0; }
    if (v.y > best) { best = v.y; bi = b0 + 1; }
    if (v.z > best) { best = v.z; bi = b0 + 2; }
    if (v.w > best) { best = v.w; bi = b0 + 3; }
  }
  unsigned vb = __float_as_uint(best);
  unsigned m = vb;
  UMAX_DPP(m, 0xB1);  // quad_perm [1,0,3,2]
  UMAX_DPP(m, 0x4E);  // quad_perm [2,3,0,1]
  unsigned t2 = (vb == m) ? (unsigned)(79 - bi) : 0u;
  UMAX_DPP(t2, 0xB1);
  UMAX_DPP(t2, 0x4E);
  if (q == 0) {
    float bestv = __uint_as_float(m);
    int bidx = 79 - (int)t2;
    float pobj = regs[row * 5 + 4];
    float sc = pobj * bestv;
    float s = (sc >= 0.05f) ? sc : NEGV;
    unsigned key = flipKey(s);
    keys[row] = key;
    ccs[row] = bestv;
    preds[row] = bidx;
    atomicAdd(&hist1[(size_t)img * 65536 + (key >> 16)], 1u);
  }
}

// ---------------- histogram scan (single level): find cutoff high-16 bin ----------------
__global__ void __launch_bounds__(256) k_scan(const unsigned* __restrict__ hist,
                                              Meta* __restrict__ meta) {
  __shared__ unsigned part[256];
  __shared__ unsigned sfx[256];
  __shared__ int s_sel;
  __shared__ unsigned s_cum;
  int img = blockIdx.x;
  int t = threadIdx.x;
  const unsigned* h = hist + (size_t)img * 65536;
  const unsigned target = (unsigned)TOPK;
  unsigned s = 0;
  const uint4* h4 = reinterpret_cast<const uint4*>(h) + (size_t)t * 64;
  for (int j = 0; j < 64; ++j) {
    uint4 v = h4[j];
    s += v.x + v.y + v.z + v.w;
  }
  part[t] = s;
  sfx[t] = s;
  __syncthreads();
  for (int d = 1; d < 256; d <<= 1) {
    unsigned v = (t + d < 256) ? sfx[t + d] : 0u;
    __syncthreads();
    sfx[t] += v;
    __syncthreads();
  }
  {
    unsigned incl = sfx[t];
    unsigned excl = incl - part[t];
    if (incl >= target && excl < target) { s_sel = t; s_cum = excl; }
  }
  __syncthreads();
  int chunk = s_sel;
  unsigned cumAbove = s_cum;
  __syncthreads();
  unsigned b = h[(size_t)chunk * 256 + t];
  part[t] = b;
  sfx[t] = b;
  __syncthreads();
  for (int d = 1; d < 256; d <<= 1) {
    unsigned v = (t + d < 256) ? sfx[t + d] : 0u;
    __syncthreads();
    sfx[t] += v;
    __syncthreads();
  }
  {
    unsigned incl = cumAbove + sfx[t];
    unsigned excl = incl - part[t];
    if (incl >= target && excl < target) {
      meta[img].b1 = (unsigned)(chunk * 256 + t);
      meta[img].c_gt = excl;
    }
  }
}

// ---------------- decode + candidate write (global) ----------------
__device__ __forceinline__ void decode_write(int img, unsigned pos, int i,
                                             const float* __restrict__ regs,
                                             const float* __restrict__ anchors,
                                             float score, float cc, int pred,
                                             float* __restrict__ cand) {
  const size_t S = (size_t)BB * CAND_CAP;
  size_t g = (size_t)img * NN + (size_t)i;
  const float* r = regs + g * 5;
  float d0 = r[0], d1 = r[1], d2 = r[2], d3 = r[3], obj = r[4];
  const float* a = anchors + (size_t)i * 4;
  float ax1 = a[0], ay1 = a[1], ax2 = a[2], ay2 = a[3];
  float aw = ax2 - ax1, ah = ay2 - ay1;
  float acx = (ax1 + ax2) * 0.5f, acy = (ay1 + ay2) * 0.5f;
  float cx = acx + d0 * aw, cy = acy + d1 * ah;
  float w = aw * expf(d2), h = ah * expf(d3);
  float hw = 0.5f * w, hh = 0.5f * h;
  float x1 = fminf(fmaxf(cx - hw, 0.0f), IMGSZ);
  float y1 = fminf(fmaxf(cy - hh, 0.0f), IMGSZ);
  float x2 = fminf(fmaxf(cx + hw, 0.0f), IMGSZ);
  float y2 = fminf(fmaxf(cy + hh, 0.0f), IMGSZ);
  size_t o = (size_t)img * CAND_CAP + pos;
  cand[0 * S + o] = x1;
  cand[1 * S + o] = y1;
  cand[2 * S + o] = x2;
  cand[3 * S + o] = y2;
  cand[4 * S + o] = obj;
  cand[5 * S + o] = cc;
  cand[6 * S + o] = (float)pred;
  cand[7 * S + o] = score;
  reinterpret_cast<unsigned*>(cand + 8 * S)[o] = (unsigned)i;
}

// ---------------- compaction: wave-aggregated atomics (1 atomic/wave) ----------------
__global__ void k_compact(const float* __restrict__ regs, const float* __restrict__ anchors,
                          const unsigned* __restrict__ keys, const float* __restrict__ ccs,
                          const int* __restrict__ preds, Meta* __restrict__ meta,
                          float* __restrict__ cand, unsigned long long* __restrict__ ties) {
  int img = blockIdx.x / BPI_C;
  int i = (blockIdx.x % BPI_C) * 256 + threadIdx.x;
  if (i >= NN) return;
  int lane = threadIdx.x & 63;
  unsigned long long lt = (1ull << lane) - 1ull;
  size_t g = (size_t)img * NN + (size_t)i;
  unsigned key = keys[g];
  unsigned k16 = key >> 16;
  unsigned b1 = meta[img].b1;

  bool above = k16 > b1;
  unsigned long long mA = __ballot(above);
  if (above) {
    int leader = __builtin_ctzll(mA);
    unsigned base = 0;
    if (lane == leader) base = atomicAdd(&meta[img].cnt, (unsigned)__popcll(mA));
    base = __shfl(base, leader);
    unsigned pos = base + (unsigned)__popcll(mA & lt);
    if (pos < CAND_CAP)
      decode_write(img, pos, i, regs, anchors, unflipKey(key), ccs[g], preds[g], cand);
  }
  bool tie = (k16 == b1);
  unsigned long long mT = __ballot(tie);
  if (tie) {
    int leader = __builtin_ctzll(mT);
    unsigned base = 0;
    if (lane == leader) base = atomicAdd(&meta[img].tie_cnt, (unsigned)__popcll(mT));
    base = __shfl(base, leader);
    unsigned tp = base + (unsigned)__popcll(mT & lt);
    if (tp < TIE_CAP)
      ties[(size_t)img * TIE_CAP + tp] =
          ((unsigned long long)key << 15) | (unsigned long long)(0x7FFFu - (unsigned)i);
  }
}

// ---------------- NMS: 4 waves per image, spin-sync (no barriers in loop) ----------------
// Boxes+areas in REGISTERS (4 cand/lane, ~20 VGPR -> no spill); keys (kh,kl) in regs.
// Per iter: local 64-bit max (3 cmp) -> 6-step DPP wave max (lane 63) -> pack
// (tag7|kh32|sec25) -> ds_write to parity-double-buffered mailbox -> volatile spin until
// all 4 tags == it+1 -> uniform combine -> one LDS broadcast winner-box read -> 4
// in-register division-free IoU tests. Deadlock-free: a slot's next write is gated by
// every wave having consumed the previous value of that parity buffer.
// Ties resolved by parallel rank-select (rank = #bigger 62-bit keys) with per-lane decode.
__global__ void __launch_bounds__(256) k_nms(const float* __restrict__ cand,
                                             const Meta* __restrict__ meta,
                                             float* __restrict__ out,
                                             const float* __restrict__ regs,
                                             const float* __restrict__ anchors,
                                             const float* __restrict__ ccs,
                                             const int* __restrict__ preds,
                                             const unsigned long long* __restrict__ ties) {
  const size_t S = (size_t)BB * CAND_CAP;
  int img = blockIdx.x;
  int tid = threadIdx.x;
  int lane = tid & 63;
  int wid = tid >> 6;

  __shared__ float4 boxo[CAND_CAP];         // offset boxes                16 KB
  __shared__ float4 pay0[CAND_CAP];         // x1,y1,x2,y2                 16 KB
  __shared__ float4 pay1[CAND_CAP];         // obj,cc,cp,score             16 KB
  __shared__ unsigned idxA[CAND_CAP];       // anchor idx                   4 KB
  __shared__ float4 lout4[MAXDET * 7 / 4];  // output staging             2.8 KB
  __shared__ unsigned long long slots[2][4];  // spin mailboxes (parity-dbuf)
  float* lout = reinterpret_cast<float*>(lout4);

  unsigned cnt = meta[img].cnt;
  unsigned c_gt = meta[img].c_gt;
  unsigned tcnt = meta[img].tie_cnt;
  if (tcnt > TIE_CAP) tcnt = TIE_CAP;
  unsigned need = (unsigned)TOPK - c_gt;
  if (need > tcnt) need = tcnt;
  int n = (int)(cnt + need);

  float x1o[4], y1o[4], x2o[4], y2o[4], area[4];
  unsigned kh[4], kl[4];

  // ---- (1) main load: 4 slots/lane, boxes to registers AND LDS ----
#pragma unroll
  for (int j = 0; j < 4; ++j) {
    int c = j * 256 + tid;
    size_t o = (size_t)img * CAND_CAP + (size_t)c;
    bool v = c < (int)cnt;
    float vx1 = cand[0 * S + o], vy1 = cand[1 * S + o];
    float vx2 = cand[2 * S + o], vy2 = cand[3 * S + o];
    float vobj = cand[4 * S + o], vcc = cand[5 * S + o];
    float vcp = cand[6 * S + o], vsc = cand[7 * S + o];
    unsigned vai = reinterpret_cast<const unsigned*>(cand + 8 * S)[o];
    if (!v) { vx1 = vy1 = vx2 = vy2 = 0.f; vobj = vcc = vcp = 0.f; vsc = NEGV; vai = 0x7FFFu; }
    float offv = vcp * 4096.0f;
    float a1 = vx1 + offv, b1 = vy1 + offv, a2 = vx2 + offv, b2 = vy2 + offv;
    x1o[j] = a1; y1o[j] = b1; x2o[j] = a2; y2o[j] = b2;
    area[j] = (a2 - a1) * (b2 - b1);
    boxo[c] = make_float4(a1, b1, a2, b2);
    pay0[c] = make_float4(vx1, vy1, vx2, vy2);
    pay1[c] = make_float4(vobj, vcc, vcp, vsc);
    idxA[c] = vai;
    kh[j] = flipKey(vsc);
    kl[j] = (((0x7FFFu - vai) & 0x7FFFu) << 10) | (unsigned)c;
  }
  if (tid < 8) slots[tid >> 2][tid & 3] = 0ull;
  __syncthreads();

  // ---- (2) tie rank-select (wave 0): rank = #ties with bigger 62-bit key ----
  if (wid == 0) {
    const unsigned long long* tptr = ties + (size_t)img * TIE_CAP;
    for (unsigned base = 0; base < tcnt; base += 64) {
      unsigned p = base + (unsigned)lane;
      unsigned long long myk = (p < tcnt) ? tptr[p] : 0ull;
      unsigned rank = 0;
      for (unsigned q2 = 0; q2 < tcnt; ++q2) {
        unsigned long long other = tptr[q2];  // wave-uniform -> broadcast, L2-resident
        rank += (other > myk) ? 1u : 0u;
      }
      if (p < tcnt && rank < need) {
        unsigned idx = 0x7FFFu - (unsigned)(myk & 0x7FFFull);
        unsigned key32 = (unsigned)(myk >> 15);
        size_t g = (size_t)img * NN + idx;
        const float* r = regs + g * 5;
        float d0 = r[0], d1 = r[1], d2 = r[2], d3 = r[3], obj = r[4];
        const float* a = anchors + (size_t)idx * 4;
        float ax1 = a[0], ay1 = a[1], ax2 = a[2], ay2 = a[3];
        float aw = ax2 - ax1, ah = ay2 - ay1;
        float acx = (ax1 + ax2) * 0.5f, acy = (ay1 + ay2) * 0.5f;
        float cx = acx + d0 * aw, cy = acy + d1 * ah;
        float w = aw * expf(d2), h = ah * expf(d3);
        float hw = 0.5f * w, hh = 0.5f * h;
        float x1 = fminf(fmaxf(cx - hw, 0.0f), IMGSZ);
        float y1 = fminf(fmaxf(cy - hh, 0.0f), IMGSZ);
        float x2 = fminf(fmaxf(cx + hw, 0.0f), IMGSZ);
        float y2 = fminf(fmaxf(cy + hh, 0.0f), IMGSZ);
        float cc = ccs[g];
        float cp = (float)preds[g];
        float offv = cp * 4096.0f;
        int c = (int)(cnt + rank);
        boxo[c] = make_float4(x1 + offv, y1 + offv, x2 + offv, y2 + offv);
        pay0[c] = make_float4(x1, y1, x2, y2);
        pay1[c] = make_float4(obj, cc, cp, unflipKey(key32));
        idxA[c] = idx;
      }
    }
  }
  __syncthreads();

  // ---- (3) tie reg-init: owning lanes pull tie slots from LDS ----
#pragma unroll
  for (int j = 0; j < 4; ++j) {
    int c = j * 256 + tid;
    if (c >= (int)cnt && c < n) {
      float4 B = boxo[c];
      float4 p1 = pay1[c];
      unsigned vai = idxA[c];
      x1o[j] = B.x; y1o[j] = B.y; x2o[j] = B.z; y2o[j] = B.w;
      area[j] = (B.z - B.x) * (B.w - B.y);
      kh[j] = flipKey(p1.w);
      kl[j] = (((0x7FFFu - vai) & 0x7FFFu) << 10) | (unsigned)c;
    }
  }
  __syncthreads();  // slots init + LDS stable before loop

  const unsigned validThr = flipKey(NEGV * 0.5f);
  volatile unsigned long long (*vslots)[4] =
      (volatile unsigned long long (*)[4])slots;

  // ---- (4) iteration loop: spin-sync, no barriers ----
  for (int it = 0; it < MAXDET; ++it) {
    // local max over 4 (64-bit order)
    unsigned mh = kh[0], ml = kl[0];
#pragma unroll
    for (int j = 1; j < 4; ++j) {
      bool g = (kh[j] > mh) || ((kh[j] == mh) && (kl[j] > ml));
      mh = g ? kh[j] : mh;
      ml = g ? kl[j] : ml;
    }
    U64MAX_DPP(mh, ml, 0x111);
    U64MAX_DPP(mh, ml, 0x112);
    U64MAX_DPP(mh, ml, 0x114);
    U64MAX_DPP(mh, ml, 0x118);
    U64MAX_DPP(mh, ml, 0x142);
    U64MAX_DPP(mh, ml, 0x143);
    unsigned Ttag = (unsigned)(it + 1);
    int par = it & 1;
    if (lane == 63) {
      unsigned long long my = ((unsigned long long)Ttag << 57) |
                              ((unsigned long long)mh << 25) |
                              (unsigned long long)(ml & 0x1FFFFFFu);
      vslots[par][wid] = my;
    }
    unsigned long long b0, b1, b2, b3;
    do { b0 = vslots[par][0]; } while ((unsigned)(b0 >> 57) != Ttag);
    do { b1 = vslots[par][1]; } while ((unsigned)(b1 >> 57) != Ttag);
    do { b2 = vslots[par][2]; } while ((unsigned)(b2 >> 57) != Ttag);
    do { b3 = vslots[par][3]; } while ((unsigned)(b3 >> 57) != Ttag);
    unsigned long long best = b0;
    if (b1 > best) best = b1;
    if (b2 > best) best = b2;
    if (b3 > best) best = b3;

    unsigned bh = (unsigned)(best >> 25);
    if (bh <= validThr) {  // no valid candidates remain: zero-fill rest, done
      for (int p = tid; p < (MAXDET - it) * 7; p += 256) lout[it * 7 + p] = 0.0f;
      break;
    }
    int slot = (int)(best & 1023u);
    float4 B = boxo[slot];  // broadcast LDS read
    float areaB = (B.z - B.x) * (B.w - B.y);
    if (wid == (it & 3) && lane == 0) {  // rotate writer wave to balance chains
      float4 p0 = pay0[slot];
      float4 p1 = pay1[slot];
      float* row = lout + it * 7;
      row[0] = p0.x; row[1] = p0.y; row[2] = p0.z; row[3] = p0.w;
      row[4] = p1.x; row[5] = p1.y; row[6] = p1.z;
    }
#pragma unroll
    for (int j = 0; j < 4; ++j) {
      int c = j * 256 + tid;
      float lx = fmaxf(B.x, x1o[j]), ly = fmaxf(B.y, y1o[j]);
      float rx = fminf(B.z, x2o[j]), ry = fminf(B.w, y2o[j]);
      float iw = fmaxf(rx - lx, 0.f), ih = fmaxf(ry - ly, 0.f);
      float inter = iw * ih;
      float uu = areaB + area[j] - inter;
      float ss = fmaf(2.0f, inter, -uu);  // exact 2i-u in the decision region (Sterbenz)
      float tt = uu * 0x1p-24f;           // exact scale; RN(i/u)>0.5 <=> ss>tt
      bool sup = (uu > 0.f && ss > tt) || (c == slot);
      if (sup) { kh[j] = 0u; kl[j] = 0u; }
    }
  }

  // ---- flush staged output rows to global ----
  __syncthreads();
  float4* go4 = reinterpret_cast<float4*>(out + (size_t)img * MAXDET * 7);
  for (int p = tid; p < MAXDET * 7 / 4; p += 256) go4[p] = lout4[p];
}

// ---------------- launch ----------------
extern "C" void kernel_launch(void* const* d_in, const int* in_sizes, int n_in,
                              void* d_out, int out_size, void* d_ws, size_t ws_size,
                              hipStream_t stream) {
  const float* regs = (const float*)d_in[0];
  const float* clses = (const float*)d_in[1];
  const float* anchors = (const float*)d_in[2];
  float* out = (float*)d_out;
  char* ws = (char*)d_ws;

  constexpr size_t HIST_BYTES = (size_t)BB * 65536 * 4;  // 4 MiB
  constexpr size_t META_OFF = HIST_BYTES;
  constexpr size_t META_BYTES = 1024;
  constexpr size_t KEYS_OFF = META_OFF + META_BYTES;
  constexpr size_t ARR_BYTES = (size_t)BB * NN * 4;
  constexpr size_t CCS_OFF = KEYS_OFF + ARR_BYTES;
  constexpr size_t PREDS_OFF = CCS_OFF + ARR_BYTES;
  constexpr size_t CAND_OFF = PREDS_OFF + ARR_BYTES;
  constexpr size_t CAND_BYTES = (size_t)10 * BB * CAND_CAP * 4;
  constexpr size_t TIES_OFF = CAND_OFF + CAND_BYTES;

  unsigned* hist1 = (unsigned*)(ws);
  Meta* meta = (Meta*)(ws + META_OFF);
  unsigned* keys = (unsigned*)(ws + KEYS_OFF);
  float* ccs = (float*)(ws + CCS_OFF);
  int* preds = (int*)(ws + PREDS_OFF);
  float* cand = (float*)(ws + CAND_OFF);
  unsigned long long* ties = (unsigned long long*)(ws + TIES_OFF);

  // zero hist1 + meta every launch (ws is not re-poisoned between replays)
  hipMemsetAsync(d_ws, 0, KEYS_OFF, stream);

  k_score<<<BB * BPI_S, 256, 0, stream>>>(regs, clses, keys, ccs, preds, hist1);
  k_scan<<<BB, 256, 0, stream>>>(hist1, meta);
  k_compact<<<BB * BPI_C, 256, 0, stream>>>(regs, anchors, keys, ccs, preds, meta, cand, ties);
  k_nms<<<BB, 256, 0, stream>>>(cand, meta, out, regs, anchors, ccs, preds, ties);
}